// Round 8
// baseline (11434.458 us; speedup 1.0000x reference)
//
#include <hip/hip_runtime.h>
#include <hip/hip_fp16.h>

typedef _Float16 f16;
typedef f16 f16x8 __attribute__((ext_vector_type(8)));
typedef f16 f16x4 __attribute__((ext_vector_type(4)));
typedef float f32x4 __attribute__((ext_vector_type(4)));
typedef float f32x16 __attribute__((ext_vector_type(16)));

#define B_ 64
#define T_ 512
#define I_ 256
#define O_ 1024
#define M_ 8
#define IM_ 2048
#define NREC 64
#define NB 96
#define THREADS 384

// ws layout (bytes)
#define OFF_X16 4096ull
#define SZ_X16  ((unsigned long long)T_ * B_ * I_ * 2)   // 16 MB, [T][B][I] f16
#define OFF_XP3 (OFF_X16 + SZ_X16)                       // 3 x [B][IM] f16
#define SZ_XP3  (3ull * B_ * IM_ * 2)
#define OFF_H2  (OFF_XP3 + SZ_XP3)                       // 2 x [B][O] f16

// barrier uint indices (64B-separated lines)
#define LEAFA(i) ((i) * 16)
#define CENTA    128
#define FLAGA(i) (192 + (i) * 16)
#define LEAFB(i) (320 + (i) * 16)
#define CENTB    448
#define FLAGB(i) (512 + (i) * 16)

// LDS layout
#define CMB_REC 147456          // 8 KB combine buffer (REC)
#define CMB_ACT 114688          // 8 KB combine buffer (ACT)
#define XPRAW   81920
#define LSE_O   122880
#define PART_O  123904
#define GATE_O  124928
#define SMEM_SZ 155648

#define WAITV(N) asm volatile("s_waitcnt vmcnt(" #N ")" ::: "memory")
#define LGKM0    asm volatile("s_waitcnt lgkmcnt(0)" ::: "memory")
#define SCHEDB   __builtin_amdgcn_sched_barrier(0)
#define BARRIER  __builtin_amdgcn_s_barrier()

// 8 x 16B plain cached loads at 32B stride (read-only x16 input)
#define ISSUE_AX(BUF, P) asm volatile( \
    "global_load_dwordx4 %0, %8, off\n\t" \
    "global_load_dwordx4 %1, %8, off offset:32\n\t" \
    "global_load_dwordx4 %2, %8, off offset:64\n\t" \
    "global_load_dwordx4 %3, %8, off offset:96\n\t" \
    "global_load_dwordx4 %4, %8, off offset:128\n\t" \
    "global_load_dwordx4 %5, %8, off offset:160\n\t" \
    "global_load_dwordx4 %6, %8, off offset:192\n\t" \
    "global_load_dwordx4 %7, %8, off offset:224" \
    : "=&v"(abuf[BUF][0]), "=&v"(abuf[BUF][1]), "=&v"(abuf[BUF][2]), "=&v"(abuf[BUF][3]), \
      "=&v"(abuf[BUF][4]), "=&v"(abuf[BUF][5]), "=&v"(abuf[BUF][6]), "=&v"(abuf[BUF][7]) \
    : "v"(P) : "memory")

// 8 x 16B coherent (device-scope) loads at 32B stride (cross-XCD state)
#define ISSUE_AS(BUF, P) asm volatile( \
    "global_load_dwordx4 %0, %8, off sc0 sc1\n\t" \
    "global_load_dwordx4 %1, %8, off offset:32 sc0 sc1\n\t" \
    "global_load_dwordx4 %2, %8, off offset:64 sc0 sc1\n\t" \
    "global_load_dwordx4 %3, %8, off offset:96 sc0 sc1\n\t" \
    "global_load_dwordx4 %4, %8, off offset:128 sc0 sc1\n\t" \
    "global_load_dwordx4 %5, %8, off offset:160 sc0 sc1\n\t" \
    "global_load_dwordx4 %6, %8, off offset:192 sc0 sc1\n\t" \
    "global_load_dwordx4 %7, %8, off offset:224 sc0 sc1" \
    : "=&v"(abuf[BUF][0]), "=&v"(abuf[BUF][1]), "=&v"(abuf[BUF][2]), "=&v"(abuf[BUF][3]), \
      "=&v"(abuf[BUF][4]), "=&v"(abuf[BUF][5]), "=&v"(abuf[BUF][6]), "=&v"(abuf[BUF][7]) \
    : "v"(P) : "memory")

// 8 x 16B coherent loads from 8 independent addresses into named array
#define ISSUE_STGA(ARR, P0,P1,P2,P3,P4,P5,P6,P7) asm volatile( \
    "global_load_dwordx4 %0, %8, off sc0 sc1\n\t" \
    "global_load_dwordx4 %1, %9, off sc0 sc1\n\t" \
    "global_load_dwordx4 %2, %10, off sc0 sc1\n\t" \
    "global_load_dwordx4 %3, %11, off sc0 sc1\n\t" \
    "global_load_dwordx4 %4, %12, off sc0 sc1\n\t" \
    "global_load_dwordx4 %5, %13, off sc0 sc1\n\t" \
    "global_load_dwordx4 %6, %14, off sc0 sc1\n\t" \
    "global_load_dwordx4 %7, %15, off sc0 sc1" \
    : "=&v"((ARR)[0]), "=&v"((ARR)[1]), "=&v"((ARR)[2]), "=&v"((ARR)[3]), \
      "=&v"((ARR)[4]), "=&v"((ARR)[5]), "=&v"((ARR)[6]), "=&v"((ARR)[7]) \
    : "v"(P0), "v"(P1), "v"(P2), "v"(P3), "v"(P4), "v"(P5), "v"(P6), "v"(P7) \
    : "memory")

// prologue issue of chunk c0k+J into buffer J (x-cached if global chunk <2)
#define GM_PRO(J) do { \
    const int c_ = c0k + (J); \
    if (c_ < 2) { const char* p_ = xrow + c_ * 256;  ISSUE_AX(J, p_); } \
    else        { const char* p_ = sprow + c_ * 256; ISSUE_AS(J, p_); } \
} while (0)

// chunk iteration: counted wait, 8 MFMA, optional reissue 3 ahead (always state)
#define GM_IT(I, WN, DOISS) do { \
    WAITV(WN); \
    _Pragma("unroll") \
    for (int kb = 0; kb < 8; ++kb) { \
        f16x8 bf = *(const f16x8*)(smem + addrB[kb] + (I) * 256); \
        if (kb & 1) acc1 = __builtin_amdgcn_mfma_f32_32x32x16_f16(abuf[(I) % 3][kb], bf, acc1, 0, 0, 0); \
        else        acc0 = __builtin_amdgcn_mfma_f32_32x32x16_f16(abuf[(I) % 3][kb], bf, acc0, 0, 0, 0); \
    } \
    SCHEDB; \
    if (DOISS) { const char* p_ = sprow + (c0k + (I) + 3) * 256; ISSUE_AS(((I) % 3), p_); } \
} while (0)

__device__ __forceinline__ void st_coh_h(f16* p, float vf) {
    union { f16 h; short s; } u; u.h = (f16)vf;
    asm volatile("global_store_short %0, %1, off sc0 sc1" :: "v"(p), "v"((int)u.s) : "memory");
}

__device__ __forceinline__ float fast_tanh(float x) {
    float e = __expf(2.f * x);
    return 1.f - 2.f / (e + 1.f);
}

__device__ __forceinline__ unsigned ld_rlx(unsigned* p) {
    return __hip_atomic_load(p, __ATOMIC_RELAXED, __HIP_MEMORY_SCOPE_AGENT);
}

__device__ __forceinline__ void post_flags(unsigned* bar, int base, unsigned v) {
    #pragma unroll
    for (int i = 0; i < 8; ++i) {
        unsigned* rp = &bar[base + i * 16];
        asm volatile("global_store_dword %0, %1, off sc0 sc1" :: "v"(rp), "v"(v) : "memory");
    }
}

__device__ __forceinline__ void arriveA(unsigned* bar, int blk, int t) {
    unsigned old = __hip_atomic_fetch_add(&bar[LEAFA(blk & 7)], 1u, __ATOMIC_RELAXED, __HIP_MEMORY_SCOPE_AGENT);
    if ((old & 7u) == 7u) {
        unsigned r = __hip_atomic_fetch_add(&bar[CENTA], 1u, __ATOMIC_RELAXED, __HIP_MEMORY_SCOPE_AGENT);
        if ((r & 7u) == 7u) post_flags(bar, FLAGA(0), (unsigned)(t + 1));
    }
}
__device__ __forceinline__ void arriveB(unsigned* bar, int a, int t) {
    unsigned old = __hip_atomic_fetch_add(&bar[LEAFB(a & 7)], 1u, __ATOMIC_RELAXED, __HIP_MEMORY_SCOPE_AGENT);
    if ((old & 3u) == 3u) {
        unsigned r = __hip_atomic_fetch_add(&bar[CENTB], 1u, __ATOMIC_RELAXED, __HIP_MEMORY_SCOPE_AGENT);
        if ((r & 7u) == 7u) post_flags(bar, FLAGB(0), (unsigned)(t + 1));
    }
}

// init: zero barriers+state, convert x [B,T,I] f32 -> x16 [T,B,I] f16
__global__ void init_kernel(const float* __restrict__ x, char* __restrict__ ws) {
    const int gid = blockIdx.x * 256 + threadIdx.x;
    if (blockIdx.x == 0) {
        for (int i = threadIdx.x; i < 1024; i += 256) ((unsigned*)ws)[i] = 0u;
    }
    f16* x16 = (f16*)(ws + OFF_X16);
    const int NQ = T_ * B_ * (I_ / 4);
    for (int q = gid; q < NQ; q += 256 * 256) {
        int t = q >> 12;
        int rem = q & 4095;
        int b = rem >> 6;
        int k4 = rem & 63;
        f32x4 v = *(const f32x4*)(x + ((size_t)b * T_ + t) * I_ + k4 * 4);
        f16x4 h;
        h[0] = (f16)v[0]; h[1] = (f16)v[1]; h[2] = (f16)v[2]; h[3] = (f16)v[3];
        *(f16x4*)(x16 + ((size_t)t * B_ + b) * I_ + k4 * 4) = h;
    }
    f16x8 z = {0, 0, 0, 0, 0, 0, 0, 0};
    f16* xp0 = (f16*)(ws + OFF_XP3);
    for (int e = gid * 8; e < B_ * IM_; e += 256 * 256 * 8) *(f16x8*)(xp0 + e) = z;
    f16* h0 = (f16*)(ws + OFF_H2);
    for (int e = gid * 8; e < B_ * O_; e += 256 * 256 * 8) *(f16x8*)(h0 + e) = z;
}

__global__ __launch_bounds__(THREADS, 1) void cwrnn_kernel(
    const float* __restrict__ x, const float* __restrict__ W_in, const float* __restrict__ b_in,
    const float* __restrict__ W_h, const float* __restrict__ W_ir, const float* __restrict__ b_ir,
    const float* __restrict__ W_hr, const float* __restrict__ periods, const float* __restrict__ shifts,
    float* __restrict__ out, char* __restrict__ ws)
{
    __shared__ __align__(16) char smem[SMEM_SZ];
    // REC: W2[32][2304] swz @0 (147456) | combine 8KB @147456
    // ACT: W1[32][1280] swz @0 (81920) | xp_raw @81920 (32768) | combine 8KB @114688
    //      lse @122880 | part @123904 | gate @124928

    unsigned* bar = (unsigned*)ws;
    const int blk = blockIdx.x, tid = threadIdx.x;
    const int lane = tid & 63, w = tid >> 6;
    const int col = lane & 31, g = lane >> 5;
    const int rg = w & 1;           // row group (rows rg*32..rg*32+31)
    const int kg = w >> 1;          // K group 0..2
    const int arow = (rg << 5) + col;

    float* ys = out;
    float* hfin = out + (size_t)B_ * T_ * O_;
    float* ps = hfin + (size_t)B_ * O_;

    if (blk < NREC) {
        // ================= x_pred recurrence blocks: cols j0..j0+31 of acts_rec =================
        const int j0 = blk * 32;
        {   // stage W2 = [W_ir | W_hr] rows j0..j0+31 into swizzled LDS (once)
            const int j = tid & 31;
            const float* ra = W_ir + (size_t)(j0 + j) * I_;
            const float* rb = W_hr + (size_t)(j0 + j) * IM_ - 256;
            for (int u = (tid >> 5); u < 288; u += 12) {
                int k0 = u * 8;
                const float* s = (k0 < 256) ? (ra + k0) : (rb + k0);
                f32x4 lo = *(const f32x4*)s;
                f32x4 hi = *(const f32x4*)(s + 4);
                f16x8 v;
                #pragma unroll
                for (int e = 0; e < 4; ++e) { v[e] = (f16)lo[e]; v[e + 4] = (f16)hi[e]; }
                *(f16x8*)(smem + j * 4608 + ((u ^ (j & 15)) << 4)) = v;
            }
        }
        const float bir = b_ir[j0 + col];
        LGKM0; BARRIER;

        int addrB[8];
        const int c0k = kg * 6;      // 18 code-chunks of 128K, 6 per K-group
        #pragma unroll
        for (int kb = 0; kb < 8; ++kb)
            addrB[kb] = col * 4608 + ((((kb << 1) + g) ^ (col & 15)) << 4) + c0k * 256;

        const char* xrow0 = (const char*)(ws + OFF_X16) + (size_t)arow * 512 + g * 16;
        f16* const xpB = (f16*)(ws + OFF_XP3);
        unsigned* fA = &bar[FLAGA(blk & 7)];
        unsigned* fB = &bar[FLAGB(blk & 7)];

        for (int t = 0; t < T_ - 1; ++t) {
            if (tid == 0) {
                while (1) {
                    int fa = (int)ld_rlx(fA);
                    int fb = (int)ld_rlx(fB);
                    if (fa >= t && fb >= t - 2) break;
                    __builtin_amdgcn_s_sleep(2);
                }
            }
            BARRIER;
            const int bi = t % 3;
            int bn = bi + 1; if (bn == 3) bn = 0;
            const f16* xpcur = xpB + (size_t)bi * B_ * IM_;
            f16* xpnxt = xpB + (size_t)bn * B_ * IM_;
            const char* sprow = (const char*)xpcur + (size_t)arow * 4096 + g * 16 - 512;
            const char* xrow = xrow0 + (size_t)t * 32768;

            f16x8 abuf[3][8];
            f32x16 acc0, acc1;
            #pragma unroll
            for (int r = 0; r < 16; ++r) { acc0[r] = 0.f; acc1[r] = 0.f; }

            GM_PRO(0); GM_PRO(1); GM_PRO(2);
            GM_IT(0, 16, 1); GM_IT(1, 16, 1); GM_IT(2, 16, 1);
            GM_IT(3, 16, 0); GM_IT(4, 8, 0); GM_IT(5, 0, 0);

            f32x16 accS;
            #pragma unroll
            for (int r = 0; r < 16; ++r) accS[r] = acc0[r] + acc1[r];

            // cross-wave K combine (two phases through 8KB)
            if (kg == 1) {
                char* cb = smem + CMB_REC + rg * 4096 + lane * 16;
                #pragma unroll
                for (int q = 0; q < 4; ++q) {
                    f32x4 v = { accS[q*4+0], accS[q*4+1], accS[q*4+2], accS[q*4+3] };
                    *(f32x4*)(cb + q * 1024) = v;
                }
            }
            LGKM0; BARRIER;
            if (kg == 0) {
                const char* cb = smem + CMB_REC + rg * 4096 + lane * 16;
                #pragma unroll
                for (int q = 0; q < 4; ++q) {
                    f32x4 v = *(const f32x4*)(cb + q * 1024);
                    accS[q*4+0] += v[0]; accS[q*4+1] += v[1];
                    accS[q*4+2] += v[2]; accS[q*4+3] += v[3];
                }
            }
            LGKM0; BARRIER;
            if (kg == 2) {
                char* cb = smem + CMB_REC + rg * 4096 + lane * 16;
                #pragma unroll
                for (int q = 0; q < 4; ++q) {
                    f32x4 v = { accS[q*4+0], accS[q*4+1], accS[q*4+2], accS[q*4+3] };
                    *(f32x4*)(cb + q * 1024) = v;
                }
            }
            LGKM0; BARRIER;
            if (kg == 0) {
                const char* cb = smem + CMB_REC + rg * 4096 + lane * 16;
                #pragma unroll
                for (int q = 0; q < 4; ++q) {
                    f32x4 v = *(const f32x4*)(cb + q * 1024);
                    accS[q*4+0] += v[0]; accS[q*4+1] += v[1];
                    accS[q*4+2] += v[2]; accS[q*4+3] += v[3];
                }
                #pragma unroll
                for (int r = 0; r < 16; ++r) {
                    int row = (r & 3) + ((r >> 2) << 3) + (g << 2) + (rg << 5);
                    st_coh_h(xpnxt + (size_t)row * IM_ + j0 + col, fast_tanh(accS[r] + bir));
                }
            }
            WAITV(0);
            BARRIER;
            if (tid == 0) arriveA(bar, blk, t);
        }
    } else {
        // ================= acts/gate/output blocks: cols o0..o0+31 =================
        const int a = blk - NREC;
        const int m = a >> 2;
        const int o0 = a * 32;
        {   // stage W1 = [W_in | W_h] rows o0..o0+31
            const int j = tid & 31;
            const float* ra = W_in + (size_t)(o0 + j) * I_;
            const float* rb = W_h + (size_t)(o0 + j) * O_ - 256;
            for (int u = (tid >> 5); u < 160; u += 12) {
                int k0 = u * 8;
                const float* s = (k0 < 256) ? (ra + k0) : (rb + k0);
                f32x4 lo = *(const f32x4*)s;
                f32x4 hi = *(const f32x4*)(s + 4);
                f16x8 v;
                #pragma unroll
                for (int e = 0; e < 4; ++e) { v[e] = (f16)lo[e]; v[e + 4] = (f16)hi[e]; }
                *(f16x8*)(smem + j * 2560 + ((u ^ (j & 15)) << 4)) = v;
            }
        }
        const float bin = b_in[o0 + col];
        const float per = periods[m], shf = shifts[m];
        LGKM0; BARRIER;

        int addrB[8];
        const int c0k = kg * 4;      // 10 code-chunks; kg0:0-3, kg1:4-7, kg2:8-9
        #pragma unroll
        for (int kb = 0; kb < 8; ++kb)
            addrB[kb] = col * 2560 + ((((kb << 1) + g) ^ (col & 15)) << 4) + c0k * 256;

        char* xp_raw = smem + XPRAW;
        float* lse_lds = (float*)(smem + LSE_O);
        float* part_lds = (float*)(smem + PART_O);
        float* gate_lds = (float*)(smem + GATE_O);

        const char* xrow0 = (const char*)(ws + OFF_X16) + (size_t)arow * 512 + g * 16;
        const f16* xpB = (const f16*)(ws + OFF_XP3);
        f16* h2 = (f16*)(ws + OFF_H2);
        unsigned* fA = &bar[FLAGA(a & 7)];
        unsigned* fB = &bar[FLAGB(a & 7)];
        float hreg[16];
        #pragma unroll
        for (int r = 0; r < 16; ++r) hreg[r] = 0.f;

        for (int t = 0; t < T_; ++t) {
            if (tid == 0) {
                while (1) {
                    int fa = (int)ld_rlx(fA);
                    int fb = (int)ld_rlx(fB);
                    if (fa >= t && fb >= t) break;
                    __builtin_amdgcn_s_sleep(2);
                }
            }
            BARRIER;
            const int bi = t % 3;
            const f16* xpcur = xpB + (size_t)bi * B_ * IM_;
            const f16* hcur = h2 + (size_t)(t & 1) * B_ * O_;
            f16* hnxt = h2 + (size_t)((t + 1) & 1) * B_ * O_;

            const char* sprow = (const char*)hcur + (size_t)arow * 2048 + g * 16 - 512;
            const char* xrow = xrow0 + (size_t)t * 32768;
            f16x8 abuf[3][8];
            f16x8 sreg[8], sreg2[8];
            f32x16 acc0, acc1;
            #pragma unroll
            for (int r = 0; r < 16; ++r) { acc0[r] = 0.f; acc1[r] = 0.f; }

            if (kg < 2) {
                GM_PRO(0); GM_PRO(1); GM_PRO(2);
                GM_IT(0, 16, 1); GM_IT(1, 16, 0); GM_IT(2, 8, 0); GM_IT(3, 0, 0);
            } else {
                // kg2: chunks 8,9 + softmax-slice staging (2 slots/lane)
                { const char* p_ = sprow + 8 * 256; ISSUE_AS(0, p_); }
                { const char* p_ = sprow + 9 * 256; ISSUE_AS(1, p_); }
                const int l = tid - 256;              // 0..127
                const int t5a = l >> 5, cga = l & 31;           // slot l
                const int t5b = (l + 128) >> 5, cgb = l & 31;   // slot l+128
                const char* sa = (const char*)xpcur + (size_t)m * 512 + cga * 16 + (size_t)t5a * 4096;
                const char* sb = (const char*)xpcur + (size_t)m * 512 + cgb * 16 + (size_t)t5b * 4096;
                ISSUE_STGA(sreg,  sa, sa + 32768, sa + 2*32768, sa + 3*32768,
                                  sa + 4*32768, sa + 5*32768, sa + 6*32768, sa + 7*32768);
                ISSUE_STGA(sreg2, sb, sb + 32768, sb + 2*32768, sb + 3*32768,
                                  sb + 4*32768, sb + 5*32768, sb + 6*32768, sb + 7*32768);
                WAITV(24);
                #pragma unroll
                for (int kb = 0; kb < 8; ++kb) {
                    f16x8 bf = *(const f16x8*)(smem + addrB[kb]);
                    if (kb & 1) acc1 = __builtin_amdgcn_mfma_f32_32x32x16_f16(abuf[0][kb], bf, acc1, 0, 0, 0);
                    else        acc0 = __builtin_amdgcn_mfma_f32_32x32x16_f16(abuf[0][kb], bf, acc0, 0, 0, 0);
                }
                WAITV(16);
                #pragma unroll
                for (int kb = 0; kb < 8; ++kb) {
                    f16x8 bf = *(const f16x8*)(smem + addrB[kb] + 256);
                    if (kb & 1) acc1 = __builtin_amdgcn_mfma_f32_32x32x16_f16(abuf[1][kb], bf, acc1, 0, 0, 0);
                    else        acc0 = __builtin_amdgcn_mfma_f32_32x32x16_f16(abuf[1][kb], bf, acc0, 0, 0, 0);
                }
                WAITV(0); SCHEDB;
                {   // park both slots into swizzled xp_raw
                    const int gswa = (cga ^ t5a) << 4;
                    const int gswb = (cgb ^ t5b) << 4;
                    #pragma unroll
                    for (int k = 0; k < 8; ++k) {
                        *(f16x8*)(xp_raw + (size_t)(t5a + (k << 3)) * 512 + gswa) = sreg[k];
                        *(f16x8*)(xp_raw + (size_t)(t5b + (k << 3)) * 512 + gswb) = sreg2[k];
                    }
                }
            }

            f32x16 accS;
            #pragma unroll
            for (int r = 0; r < 16; ++r) accS[r] = acc0[r] + acc1[r];

            if (kg == 1) {
                char* cb = smem + CMB_ACT + rg * 4096 + lane * 16;
                #pragma unroll
                for (int q = 0; q < 4; ++q) {
                    f32x4 v = { accS[q*4+0], accS[q*4+1], accS[q*4+2], accS[q*4+3] };
                    *(f32x4*)(cb + q * 1024) = v;
                }
            }
            LGKM0; BARRIER;
            // phase: lse (tid<256) + kg0 folds kg1 tile
            if (tid < 256) {
                int i = tid;
                int gq = i >> 3, r2 = (i & 7) * 2;
                float s = 0.f;
                #pragma unroll 8
                for (int b = 0; b < B_; ++b)
                    s += __expf((float)*(const f16*)(xp_raw + b * 512 + ((gq ^ (b & 7)) << 4) + r2));
                lse_lds[i] = __logf(s);
            }
            if (kg == 0) {
                const char* cb = smem + CMB_ACT + rg * 4096 + lane * 16;
                #pragma unroll
                for (int q = 0; q < 4; ++q) {
                    f32x4 v = *(const f32x4*)(cb + q * 1024);
                    accS[q*4+0] += v[0]; accS[q*4+1] += v[1];
                    accS[q*4+2] += v[2]; accS[q*4+3] += v[3];
                }
            }
            LGKM0; BARRIER;
            // phase: part (tid<256) + kg2 stores its tile
            if (kg == 2) {
                char* cb = smem + CMB_ACT + rg * 4096 + lane * 16;
                #pragma unroll
                for (int q = 0; q < 4; ++q) {
                    f32x4 v = { accS[q*4+0], accS[q*4+1], accS[q*4+2], accS[q*4+3] };
                    *(f32x4*)(cb + q * 1024) = v;
                }
            }
            if (tid < 256) {
                int b = tid >> 2, q = tid & 3;
                const float* xr = x + ((size_t)b * T_ + t) * I_ + q * 64;
                float s = 0.f;
                #pragma unroll
                for (int k = 0; k < 8; ++k) {
                    f16x8 xp8 = *(const f16x8*)(xp_raw + (size_t)b * 512 + ((((q << 3) + k) ^ (b & 7)) << 4));
                    f32x4 xa = *(const f32x4*)(xr + k * 8);
                    f32x4 xb2 = *(const f32x4*)(xr + k * 8 + 4);
                    #pragma unroll
                    for (int jj = 0; jj < 4; ++jj)
                        s += ((float)xp8[jj] - lse_lds[(q << 6) + (k << 3) + jj]) * xa[jj];
                    #pragma unroll
                    for (int jj = 0; jj < 4; ++jj)
                        s += ((float)xp8[jj + 4] - lse_lds[(q << 6) + (k << 3) + 4 + jj]) * xb2[jj];
                }
                part_lds[tid] = s;
            }
            LGKM0; BARRIER;
            // phase: gate (tid<64) + kg0 folds kg2 tile
            if (tid < B_) {
                float s = part_lds[tid * 4] + part_lds[tid * 4 + 1] + part_lds[tid * 4 + 2] + part_lds[tid * 4 + 3];
                float mp = (s * (1.f / 256.f)) * per;
                gate_lds[tid] = 0.5f * (sinf((float)t * mp + shf) + 1.f);
                if ((a & 3) == 0) ps[((size_t)tid * T_ + t) * M_ + m] = mp;
            }
            if (kg == 0) {
                const char* cb = smem + CMB_ACT + rg * 4096 + lane * 16;
                #pragma unroll
                for (int q = 0; q < 4; ++q) {
                    f32x4 v = *(const f32x4*)(cb + q * 1024);
                    accS[q*4+0] += v[0]; accS[q*4+1] += v[1];
                    accS[q*4+2] += v[2]; accS[q*4+3] += v[3];
                }
            }
            LGKM0; BARRIER;
            if (kg == 0) {
                #pragma unroll
                for (int r = 0; r < 16; ++r) {
                    int row = (r & 3) + ((r >> 2) << 3) + (g << 2) + (rg << 5);
                    float gt = gate_lds[row];
                    float av = fast_tanh(accS[r] + bin);
                    float y = (1.f - gt) * av + gt * hreg[r];
                    hreg[r] = y;
                    st_coh_h(hnxt + (size_t)row * O_ + o0 + col, y);
                    ys[((size_t)row * T_ + t) * O_ + o0 + col] = y;
                    if (t == T_ - 1) hfin[(size_t)row * O_ + o0 + col] = y;
                }
            }
            WAITV(0);
            BARRIER;
            if (tid == 0) arriveB(bar, a, t);
        }
    }
}

extern "C" void kernel_launch(void* const* d_in, const int* in_sizes, int n_in,
                              void* d_out, int out_size, void* d_ws, size_t ws_size,
                              hipStream_t stream) {
    const float* x    = (const float*)d_in[0];
    const float* W_in = (const float*)d_in[1];
    const float* b_in = (const float*)d_in[2];
    const float* W_h  = (const float*)d_in[3];
    const float* W_ir = (const float*)d_in[4];
    const float* b_ir = (const float*)d_in[5];
    const float* W_hr = (const float*)d_in[6];
    const float* per  = (const float*)d_in[7];
    const float* shf  = (const float*)d_in[8];

    hipLaunchKernelGGL(init_kernel, dim3(256), dim3(256), 0, stream,
                       x, (char*)d_ws);
    hipLaunchKernelGGL(cwrnn_kernel, dim3(NB), dim3(THREADS), 0, stream,
                       x, W_in, b_in, W_h, W_ir, b_ir, W_hr, per, shf,
                       (float*)d_out, (char*)d_ws);
}

// Round 9
// 5470.733 us; speedup vs baseline: 2.0901x; 2.0901x over previous
//
#include <hip/hip_runtime.h>
#include <hip/hip_fp16.h>

typedef _Float16 f16;
typedef f16 f16x8 __attribute__((ext_vector_type(8)));
typedef f16 f16x4 __attribute__((ext_vector_type(4)));
typedef float f32x4 __attribute__((ext_vector_type(4)));
typedef float f32x16 __attribute__((ext_vector_type(16)));

#define B_ 64
#define T_ 512
#define I_ 256
#define O_ 1024
#define M_ 8
#define IM_ 2048
#define NRECB 128
#define NB 192
#define THREADS 256

// ws layout (bytes)
#define OFF_X16 4096ull
#define SZ_X16  ((unsigned long long)T_ * B_ * I_ * 2)   // 16 MB, [T][B][I] f16
#define OFF_XP3 (OFF_X16 + SZ_X16)                       // 3 x [B][IM] f16
#define SZ_XP3  (3ull * B_ * IM_ * 2)
#define OFF_H2  (OFF_XP3 + SZ_XP3)                       // 2 x [B][O] f16

// barrier uint indices (64B-separated lines)
#define LEAFA(i) ((i) * 16)
#define CENTA    128
#define FLAGA(i) (192 + (i) * 16)
#define LEAFB(i) (320 + (i) * 16)
#define CENTB    448
#define FLAGB(i) (512 + (i) * 16)

// LDS layout
#define CMB_REC 147456          // 12 KB combine (REC): 3 waves x 4 KB
#define XPRAW   81920           // ACT: xp slice [64][256] f16 swizzled
#define CMB_ACT 114688          // 12 KB combine (ACT)
#define LSE_O   126976
#define PART_O  128000
#define GATE_O  129024
#define SMEM_SZ 159744

#define WAITV(N) asm volatile("s_waitcnt vmcnt(" #N ")" ::: "memory")
#define LGKM0    asm volatile("s_waitcnt lgkmcnt(0)" ::: "memory")
#define SCHEDB   __builtin_amdgcn_sched_barrier(0)
#define BARRIER  __builtin_amdgcn_s_barrier()

// 8 x 16B plain cached loads, 32B stride (read-only x16 input)
#define ISSUE_AX(BUF, P) asm volatile( \
    "global_load_dwordx4 %0, %8, off\n\t" \
    "global_load_dwordx4 %1, %8, off offset:32\n\t" \
    "global_load_dwordx4 %2, %8, off offset:64\n\t" \
    "global_load_dwordx4 %3, %8, off offset:96\n\t" \
    "global_load_dwordx4 %4, %8, off offset:128\n\t" \
    "global_load_dwordx4 %5, %8, off offset:160\n\t" \
    "global_load_dwordx4 %6, %8, off offset:192\n\t" \
    "global_load_dwordx4 %7, %8, off offset:224" \
    : "=&v"(abuf[BUF][0]), "=&v"(abuf[BUF][1]), "=&v"(abuf[BUF][2]), "=&v"(abuf[BUF][3]), \
      "=&v"(abuf[BUF][4]), "=&v"(abuf[BUF][5]), "=&v"(abuf[BUF][6]), "=&v"(abuf[BUF][7]) \
    : "v"(P) : "memory")

// 8 x 16B coherent (device-scope) loads, 32B stride (cross-XCD state)
#define ISSUE_AS(BUF, P) asm volatile( \
    "global_load_dwordx4 %0, %8, off sc0 sc1\n\t" \
    "global_load_dwordx4 %1, %8, off offset:32 sc0 sc1\n\t" \
    "global_load_dwordx4 %2, %8, off offset:64 sc0 sc1\n\t" \
    "global_load_dwordx4 %3, %8, off offset:96 sc0 sc1\n\t" \
    "global_load_dwordx4 %4, %8, off offset:128 sc0 sc1\n\t" \
    "global_load_dwordx4 %5, %8, off offset:160 sc0 sc1\n\t" \
    "global_load_dwordx4 %6, %8, off offset:192 sc0 sc1\n\t" \
    "global_load_dwordx4 %7, %8, off offset:224 sc0 sc1" \
    : "=&v"(abuf[BUF][0]), "=&v"(abuf[BUF][1]), "=&v"(abuf[BUF][2]), "=&v"(abuf[BUF][3]), \
      "=&v"(abuf[BUF][4]), "=&v"(abuf[BUF][5]), "=&v"(abuf[BUF][6]), "=&v"(abuf[BUF][7]) \
    : "v"(P) : "memory")

// 8 x 16B coherent loads from 8 independent addresses into named array
#define ISSUE8P(ARR, P0,P1,P2,P3,P4,P5,P6,P7) asm volatile( \
    "global_load_dwordx4 %0, %8, off sc0 sc1\n\t" \
    "global_load_dwordx4 %1, %9, off sc0 sc1\n\t" \
    "global_load_dwordx4 %2, %10, off sc0 sc1\n\t" \
    "global_load_dwordx4 %3, %11, off sc0 sc1\n\t" \
    "global_load_dwordx4 %4, %12, off sc0 sc1\n\t" \
    "global_load_dwordx4 %5, %13, off sc0 sc1\n\t" \
    "global_load_dwordx4 %6, %14, off sc0 sc1\n\t" \
    "global_load_dwordx4 %7, %15, off sc0 sc1" \
    : "=&v"((ARR)[0]), "=&v"((ARR)[1]), "=&v"((ARR)[2]), "=&v"((ARR)[3]), \
      "=&v"((ARR)[4]), "=&v"((ARR)[5]), "=&v"((ARR)[6]), "=&v"((ARR)[7]) \
    : "v"(P0), "v"(P1), "v"(P2), "v"(P3), "v"(P4), "v"(P5), "v"(P6), "v"(P7) \
    : "memory")

// one chunk: counted wait (+sched fence, rule #18), 8 MFMA
#define CH(I, WN) do { \
    WAITV(WN); SCHEDB; \
    _Pragma("unroll") \
    for (int kb = 0; kb < 8; ++kb) { \
        f16x8 bf = *(const f16x8*)(smem + addrB[kb] + (I) * 256); \
        if (kb & 1) acc1 = __builtin_amdgcn_mfma_f32_32x32x16_f16(abuf[I][kb], bf, acc1, 0, 0, 0); \
        else        acc0 = __builtin_amdgcn_mfma_f32_32x32x16_f16(abuf[I][kb], bf, acc0, 0, 0, 0); \
    } \
} while (0)

__device__ __forceinline__ void st_coh_h(f16* p, float vf) {
    union { f16 h; short s; } u; u.h = (f16)vf;
    asm volatile("global_store_short %0, %1, off sc0 sc1" :: "v"(p), "v"((int)u.s) : "memory");
}

__device__ __forceinline__ float fast_tanh(float x) {
    float e = __expf(2.f * x);
    return 1.f - 2.f / (e + 1.f);
}

__device__ __forceinline__ unsigned ld_rlx(unsigned* p) {
    return __hip_atomic_load(p, __ATOMIC_RELAXED, __HIP_MEMORY_SCOPE_AGENT);
}

__device__ __forceinline__ void post_flags(unsigned* bar, int base, unsigned v) {
    #pragma unroll
    for (int i = 0; i < 8; ++i) {
        unsigned* rp = &bar[base + i * 16];
        asm volatile("global_store_dword %0, %1, off sc0 sc1" :: "v"(rp), "v"(v) : "memory");
    }
}

// REC: 128 arrivals -> 8 leaves x 16 -> central x 8 -> 8 replicated flags
__device__ __forceinline__ void arriveA(unsigned* bar, int blk, int t) {
    unsigned old = __hip_atomic_fetch_add(&bar[LEAFA(blk & 7)], 1u, __ATOMIC_RELAXED, __HIP_MEMORY_SCOPE_AGENT);
    if (old % 16u == 15u) {
        unsigned r = __hip_atomic_fetch_add(&bar[CENTA], 1u, __ATOMIC_RELAXED, __HIP_MEMORY_SCOPE_AGENT);
        if ((r & 7u) == 7u) post_flags(bar, FLAGA(0), (unsigned)(t + 1));
    }
}
// ACT: 64 arrivals -> 8 leaves x 8 -> central x 8 -> 8 replicated flags
__device__ __forceinline__ void arriveB(unsigned* bar, int a, int t) {
    unsigned old = __hip_atomic_fetch_add(&bar[LEAFB(a & 7)], 1u, __ATOMIC_RELAXED, __HIP_MEMORY_SCOPE_AGENT);
    if ((old & 7u) == 7u) {
        unsigned r = __hip_atomic_fetch_add(&bar[CENTB], 1u, __ATOMIC_RELAXED, __HIP_MEMORY_SCOPE_AGENT);
        if ((r & 7u) == 7u) post_flags(bar, FLAGB(0), (unsigned)(t + 1));
    }
}

// init: zero barriers+state, convert x [B,T,I] f32 -> x16 [T,B,I] f16
__global__ void init_kernel(const float* __restrict__ x, char* __restrict__ ws) {
    const int gid = blockIdx.x * 256 + threadIdx.x;
    if (blockIdx.x == 0) {
        for (int i = threadIdx.x; i < 1024; i += 256) ((unsigned*)ws)[i] = 0u;
    }
    f16* x16 = (f16*)(ws + OFF_X16);
    const int NQ = T_ * B_ * (I_ / 4);
    for (int q = gid; q < NQ; q += 256 * 256) {
        int t = q >> 12;
        int rem = q & 4095;
        int b = rem >> 6;
        int k4 = rem & 63;
        f32x4 v = *(const f32x4*)(x + ((size_t)b * T_ + t) * I_ + k4 * 4);
        f16x4 h;
        h[0] = (f16)v[0]; h[1] = (f16)v[1]; h[2] = (f16)v[2]; h[3] = (f16)v[3];
        *(f16x4*)(x16 + ((size_t)t * B_ + b) * I_ + k4 * 4) = h;
    }
    f16x8 z = {0, 0, 0, 0, 0, 0, 0, 0};
    f16* xp0 = (f16*)(ws + OFF_XP3);
    for (int e = gid * 8; e < B_ * IM_; e += 256 * 256 * 8) *(f16x8*)(xp0 + e) = z;
    f16* h0 = (f16*)(ws + OFF_H2);
    for (int e = gid * 8; e < B_ * O_; e += 256 * 256 * 8) *(f16x8*)(h0 + e) = z;
}

__global__ __launch_bounds__(THREADS, 1) void cwrnn_kernel(
    const float* __restrict__ x, const float* __restrict__ W_in, const float* __restrict__ b_in,
    const float* __restrict__ W_h, const float* __restrict__ W_ir, const float* __restrict__ b_ir,
    const float* __restrict__ W_hr, const float* __restrict__ periods, const float* __restrict__ shifts,
    float* __restrict__ out, char* __restrict__ ws)
{
    __shared__ __align__(16) char smem[SMEM_SZ];
    // REC: W2[32][2304] swz @0 (147456) | combine 12KB @147456
    // ACT: W1[32][1280] swz @0 (81920) | xp_raw @81920 (32KB) | combine 12KB @114688
    //      lse @126976 | part @128000 | gate @129024

    unsigned* bar = (unsigned*)ws;
    const int blk = blockIdx.x, tid = threadIdx.x;
    const int lane = tid & 63, w = tid >> 6;    // w = kg (K group 0..3)
    const int col = lane & 31, g = lane >> 5;

    float* ys = out;
    float* hfin = out + (size_t)B_ * T_ * O_;
    float* ps = hfin + (size_t)B_ * O_;

    if (blk < NRECB) {
        // ========== REC: block = (col-group cg, row-half rh); 32 rows x 32 cols ==========
        const int cg = blk >> 1, rh = blk & 1;
        const int j0 = cg * 32;
        const int row0 = rh * 32;
        const int arow = row0 + col;
        {   // stage W2 = [W_ir | W_hr] rows j0..j0+31 into swizzled LDS (once)
            const int j = tid & 31;
            const float* ra = W_ir + (size_t)(j0 + j) * I_;
            const float* rb = W_hr + (size_t)(j0 + j) * IM_ - 256;
            for (int u = (tid >> 5); u < 288; u += 8) {
                int k0 = u * 8;
                const float* s = (k0 < 256) ? (ra + k0) : (rb + k0);
                f32x4 lo = *(const f32x4*)s;
                f32x4 hi = *(const f32x4*)(s + 4);
                f16x8 v;
                #pragma unroll
                for (int e = 0; e < 4; ++e) { v[e] = (f16)lo[e]; v[e + 4] = (f16)hi[e]; }
                *(f16x8*)(smem + j * 4608 + ((u ^ (j & 15)) << 4)) = v;
            }
        }
        const float bir = b_ir[j0 + col];
        LGKM0; BARRIER;

        // K chunks (128 f16 each, 18 total): kg0:0-4 (0,1 = x cached), kg1:5-9, kg2:10-13, kg3:14-17
        const int c0k = (w == 0) ? 0 : (w == 1) ? 5 : (w == 2) ? 10 : 14;
        int addrB[8];
        #pragma unroll
        for (int kb = 0; kb < 8; ++kb)
            addrB[kb] = col * 4608 + ((((kb << 1) + g) ^ (col & 15)) << 4) + c0k * 256;

        const char* xrow0 = (const char*)(ws + OFF_X16) + (size_t)arow * 512 + g * 16;
        f16* const xpB = (f16*)(ws + OFF_XP3);
        unsigned* fA = &bar[FLAGA(blk & 7)];
        unsigned* fB = &bar[FLAGB(blk & 7)];

        for (int t = 0; t < T_ - 1; ++t) {
            if (tid == 0) {
                while (1) {
                    int fa = (int)ld_rlx(fA);
                    int fb = (int)ld_rlx(fB);
                    if (fa >= t && fb >= t - 1) break;   // fixed race: was t-2
                    __builtin_amdgcn_s_sleep(2);
                }
            }
            BARRIER;
            const int bi = t % 3;
            int bn = bi + 1; if (bn == 3) bn = 0;
            const f16* xpcur = xpB + (size_t)bi * B_ * IM_;
            f16* xpnxt = xpB + (size_t)bn * B_ * IM_;
            const char* sprow = (const char*)xpcur + (size_t)arow * 4096 + g * 16 - 512;
            const char* xrow = xrow0 + (size_t)t * 32768;

            f16x8 abuf[5][8];
            f32x16 acc0, acc1;
            #pragma unroll
            for (int r = 0; r < 16; ++r) { acc0[r] = 0.f; acc1[r] = 0.f; }

            if (w == 0) {
                ISSUE_AX(0, xrow); ISSUE_AX(1, (xrow + 256));
                ISSUE_AS(2, (sprow + 2 * 256)); ISSUE_AS(3, (sprow + 3 * 256)); ISSUE_AS(4, (sprow + 4 * 256));
                CH(0, 32); CH(1, 24); CH(2, 16); CH(3, 8); CH(4, 0);
            } else if (w == 1) {
                ISSUE_AS(0, (sprow + 5 * 256)); ISSUE_AS(1, (sprow + 6 * 256)); ISSUE_AS(2, (sprow + 7 * 256));
                ISSUE_AS(3, (sprow + 8 * 256)); ISSUE_AS(4, (sprow + 9 * 256));
                CH(0, 32); CH(1, 24); CH(2, 16); CH(3, 8); CH(4, 0);
            } else if (w == 2) {
                ISSUE_AS(0, (sprow + 10 * 256)); ISSUE_AS(1, (sprow + 11 * 256));
                ISSUE_AS(2, (sprow + 12 * 256)); ISSUE_AS(3, (sprow + 13 * 256));
                CH(0, 24); CH(1, 16); CH(2, 8); CH(3, 0);
            } else {
                ISSUE_AS(0, (sprow + 14 * 256)); ISSUE_AS(1, (sprow + 15 * 256));
                ISSUE_AS(2, (sprow + 16 * 256)); ISSUE_AS(3, (sprow + 17 * 256));
                CH(0, 24); CH(1, 16); CH(2, 8); CH(3, 0);
            }

            f32x16 accS;
            #pragma unroll
            for (int r = 0; r < 16; ++r) accS[r] = acc0[r] + acc1[r];
            if (w > 0) {
                char* cb = smem + CMB_REC + (w - 1) * 4096 + lane * 16;
                #pragma unroll
                for (int q = 0; q < 4; ++q) {
                    f32x4 v = { accS[q*4+0], accS[q*4+1], accS[q*4+2], accS[q*4+3] };
                    *(f32x4*)(cb + q * 1024) = v;
                }
            }
            LGKM0; BARRIER;
            if (w == 0) {
                #pragma unroll
                for (int wv = 0; wv < 3; ++wv) {
                    const char* cb = smem + CMB_REC + wv * 4096 + lane * 16;
                    #pragma unroll
                    for (int q = 0; q < 4; ++q) {
                        f32x4 v = *(const f32x4*)(cb + q * 1024);
                        accS[q*4+0] += v[0]; accS[q*4+1] += v[1];
                        accS[q*4+2] += v[2]; accS[q*4+3] += v[3];
                    }
                }
                #pragma unroll
                for (int r = 0; r < 16; ++r) {
                    int rloc = (r & 3) + ((r >> 2) << 3) + (g << 2);
                    st_coh_h(xpnxt + (size_t)(row0 + rloc) * IM_ + j0 + col, fast_tanh(accS[r] + bir));
                }
            }
            WAITV(0);
            BARRIER;
            if (tid == 0) arriveA(bar, blk, t);
        }
    } else {
        // ========== ACT: block = (col-group colg, row-half rh); 32 rows x 32 cols ==========
        const int a = blk - NRECB;
        const int colg = a >> 1, rh = a & 1;
        const int m = colg >> 2;
        const int o0 = colg * 32;
        const int row0 = rh * 32;
        const int arow = row0 + col;
        {   // stage W1 = [W_in | W_h] rows o0..o0+31
            const int j = tid & 31;
            const float* ra = W_in + (size_t)(o0 + j) * I_;
            const float* rb = W_h + (size_t)(o0 + j) * O_ - 256;
            for (int u = (tid >> 5); u < 160; u += 8) {
                int k0 = u * 8;
                const float* s = (k0 < 256) ? (ra + k0) : (rb + k0);
                f32x4 lo = *(const f32x4*)s;
                f32x4 hi = *(const f32x4*)(s + 4);
                f16x8 v;
                #pragma unroll
                for (int e = 0; e < 4; ++e) { v[e] = (f16)lo[e]; v[e + 4] = (f16)hi[e]; }
                *(f16x8*)(smem + j * 2560 + ((u ^ (j & 15)) << 4)) = v;
            }
        }
        const float bin = b_in[o0 + col];
        const float per = periods[m], shf = shifts[m];
        LGKM0; BARRIER;

        // K chunks (10 total): kg0:0-2 (0,1 = x cached), kg1:3-5, kg2:6-7 +stage, kg3:8-9 +stage
        const int c0k = (w == 0) ? 0 : (w == 1) ? 3 : (w == 2) ? 6 : 8;
        int addrB[8];
        #pragma unroll
        for (int kb = 0; kb < 8; ++kb)
            addrB[kb] = col * 2560 + ((((kb << 1) + g) ^ (col & 15)) << 4) + c0k * 256;

        char* xp_raw = smem + XPRAW;
        float* lse_lds = (float*)(smem + LSE_O);
        float* part_lds = (float*)(smem + PART_O);
        float* gate_lds = (float*)(smem + GATE_O);

        const char* xrow0 = (const char*)(ws + OFF_X16) + (size_t)arow * 512 + g * 16;
        const f16* xpB = (const f16*)(ws + OFF_XP3);
        f16* h2 = (f16*)(ws + OFF_H2);
        unsigned* fA = &bar[FLAGA(a & 7)];
        unsigned* fB = &bar[FLAGB(a & 7)];
        float hreg[16];
        #pragma unroll
        for (int r = 0; r < 16; ++r) hreg[r] = 0.f;

        // staging geometry: slot s = tid-128 (kg2: 0..63, kg3: 64..127)
        const int s_ = tid - 128;
        const int cg2 = s_ & 31;
        const int r0s = (s_ >> 5) << 4;     // 0,16,32,48

        for (int t = 0; t < T_; ++t) {
            if (tid == 0) {
                while (1) {
                    int fa = (int)ld_rlx(fA);
                    int fb = (int)ld_rlx(fB);
                    if (fa >= t && fb >= t) break;
                    __builtin_amdgcn_s_sleep(2);
                }
            }
            BARRIER;
            const int bi = t % 3;
            const f16* xpcur = xpB + (size_t)bi * B_ * IM_;
            const f16* hcur = h2 + (size_t)(t & 1) * B_ * O_;
            f16* hnxt = h2 + (size_t)((t + 1) & 1) * B_ * O_;

            const char* sprow = (const char*)hcur + (size_t)arow * 2048 + g * 16 - 512;
            const char* xrow = xrow0 + (size_t)t * 32768;
            f16x8 abuf[3][8];
            f16x8 sregA[8], sregB[8];
            f32x16 acc0, acc1;
            #pragma unroll
            for (int r = 0; r < 16; ++r) { acc0[r] = 0.f; acc1[r] = 0.f; }

            if (w == 0) {
                ISSUE_AX(0, xrow); ISSUE_AX(1, (xrow + 256)); ISSUE_AS(2, (sprow + 2 * 256));
                CH(0, 16); CH(1, 8); CH(2, 0);
            } else if (w == 1) {
                ISSUE_AS(0, (sprow + 3 * 256)); ISSUE_AS(1, (sprow + 4 * 256)); ISSUE_AS(2, (sprow + 5 * 256));
                CH(0, 16); CH(1, 8); CH(2, 0);
            } else {
                const int ca = (w == 2) ? 6 : 8;
                ISSUE_AS(0, (sprow + ca * 256)); ISSUE_AS(1, (sprow + (ca + 1) * 256));
                const char* xb = (const char*)xpcur + (size_t)m * 512 + (size_t)cg2 * 16 + (size_t)r0s * 4096;
                ISSUE8P(sregA, xb, xb + 4096, xb + 2*4096, xb + 3*4096,
                               xb + 4*4096, xb + 5*4096, xb + 6*4096, xb + 7*4096);
                ISSUE8P(sregB, (xb + 8*4096), xb + 9*4096, xb + 10*4096, xb + 11*4096,
                               xb + 12*4096, xb + 13*4096, xb + 14*4096, xb + 15*4096);
                CH(0, 24); CH(1, 16);
                WAITV(0); SCHEDB;
                #pragma unroll
                for (int k = 0; k < 8; ++k) {
                    int b0 = r0s + k;
                    *(f16x8*)(xp_raw + (size_t)b0 * 512 + ((cg2 ^ (b0 & 7)) << 4)) = sregA[k];
                    int b1 = r0s + 8 + k;
                    *(f16x8*)(xp_raw + (size_t)b1 * 512 + ((cg2 ^ (b1 & 7)) << 4)) = sregB[k];
                }
            }

            f32x16 accS;
            #pragma unroll
            for (int r = 0; r < 16; ++r) accS[r] = acc0[r] + acc1[r];
            if (w > 0) {
                char* cb = smem + CMB_ACT + (w - 1) * 4096 + lane * 16;
                #pragma unroll
                for (int q = 0; q < 4; ++q) {
                    f32x4 v = { accS[q*4+0], accS[q*4+1], accS[q*4+2], accS[q*4+3] };
                    *(f32x4*)(cb + q * 1024) = v;
                }
            }
            LGKM0; BARRIER;
            // P1: lse over batch (all 256 threads); wave0 folds combine tiles
            {
                int i = tid;
                int gq = i >> 3, r2 = (i & 7) * 2;
                float s = 0.f;
                #pragma unroll 8
                for (int b = 0; b < B_; ++b)
                    s += __expf((float)*(const f16*)(xp_raw + b * 512 + ((gq ^ (b & 7)) << 4) + r2));
                lse_lds[i] = __logf(s);
            }
            if (w == 0) {
                #pragma unroll
                for (int wv = 0; wv < 3; ++wv) {
                    const char* cb = smem + CMB_ACT + wv * 4096 + lane * 16;
                    #pragma unroll
                    for (int q = 0; q < 4; ++q) {
                        f32x4 v = *(const f32x4*)(cb + q * 1024);
                        accS[q*4+0] += v[0]; accS[q*4+1] += v[1];
                        accS[q*4+2] += v[2]; accS[q*4+3] += v[3];
                    }
                }
            }
            LGKM0; BARRIER;
            // P2: mean-surprisal partial dots (b, quarter)
            {
                int b = tid >> 2, q = tid & 3;
                const float* xr = x + ((size_t)b * T_ + t) * I_ + q * 64;
                float s = 0.f;
                #pragma unroll
                for (int k = 0; k < 8; ++k) {
                    f16x8 xp8 = *(const f16x8*)(xp_raw + (size_t)b * 512 + ((((q << 3) + k) ^ (b & 7)) << 4));
                    f32x4 xa = *(const f32x4*)(xr + k * 8);
                    f32x4 xb2 = *(const f32x4*)(xr + k * 8 + 4);
                    #pragma unroll
                    for (int jj = 0; jj < 4; ++jj)
                        s += ((float)xp8[jj] - lse_lds[(q << 6) + (k << 3) + jj]) * xa[jj];
                    #pragma unroll
                    for (int jj = 0; jj < 4; ++jj)
                        s += ((float)xp8[jj + 4] - lse_lds[(q << 6) + (k << 3) + 4 + jj]) * xb2[jj];
                }
                part_lds[tid] = s;
            }
            LGKM0; BARRIER;
            // P3: gate for all 64 batch rows
            if (tid < B_) {
                float s = part_lds[tid * 4] + part_lds[tid * 4 + 1] + part_lds[tid * 4 + 2] + part_lds[tid * 4 + 3];
                float mp = (s * (1.f / 256.f)) * per;
                gate_lds[tid] = 0.5f * (sinf((float)t * mp + shf) + 1.f);
                if ((a & 7) == 0) ps[((size_t)tid * T_ + t) * M_ + m] = mp;
            }
            LGKM0; BARRIER;
            // P4: wave0 blends + writes outputs/state
            if (w == 0) {
                #pragma unroll
                for (int r = 0; r < 16; ++r) {
                    int rloc = (r & 3) + ((r >> 2) << 3) + (g << 2);
                    int row = row0 + rloc;
                    float gt = gate_lds[row];
                    float av = fast_tanh(accS[r] + bin);
                    float y = (1.f - gt) * av + gt * hreg[r];
                    hreg[r] = y;
                    st_coh_h(hnxt + (size_t)row * O_ + o0 + col, y);
                    ys[((size_t)row * T_ + t) * O_ + o0 + col] = y;
                    if (t == T_ - 1) hfin[(size_t)row * O_ + o0 + col] = y;
                }
            }
            WAITV(0);
            BARRIER;
            if (tid == 0) arriveB(bar, a, t);
        }
    }
}

extern "C" void kernel_launch(void* const* d_in, const int* in_sizes, int n_in,
                              void* d_out, int out_size, void* d_ws, size_t ws_size,
                              hipStream_t stream) {
    const float* x    = (const float*)d_in[0];
    const float* W_in = (const float*)d_in[1];
    const float* b_in = (const float*)d_in[2];
    const float* W_h  = (const float*)d_in[3];
    const float* W_ir = (const float*)d_in[4];
    const float* b_ir = (const float*)d_in[5];
    const float* W_hr = (const float*)d_in[6];
    const float* per  = (const float*)d_in[7];
    const float* shf  = (const float*)d_in[8];

    hipLaunchKernelGGL(init_kernel, dim3(256), dim3(256), 0, stream,
                       x, (char*)d_ws);
    hipLaunchKernelGGL(cwrnn_kernel, dim3(NB), dim3(THREADS), 0, stream,
                       x, W_in, b_in, W_h, W_ir, b_ir, W_hr, per, shf,
                       (float*)d_out, (char*)d_ws);
}